// Round 2
// baseline (520.974 us; speedup 1.0000x reference)
//
#include <hip/hip_runtime.h>
#include <hip/hip_bf16.h>
#include <stdint.h>

// GAT forward, N=8192, IN=256, OUT=128. Inputs fp32 (adj int32), output fp32.
// softmax_j(a1_i + a2_j | adj) == adj_ij*exp(a2_j)/sum_j adj_ij*exp(a2_j)  (a1 cancels)
// -> out = (adj @ (w*h)) / (adj @ w). adj carries 1 bit/elem but arrives as int32
// (268 MB). v5: prepass packs adj -> 8 MB bitmask with a coalesced __ballot stream
// (that pass IS the 268 MB roofline read); k_agg reads the 8 MB mask (L2-resident),
// expands bits->bf16 in-register, and LDS-reduces the 4 waves of a block before
// global atomics (18.9M -> 2.36M atomics). v3/v4 evidence: occupancy pinned at
// ~20% (72 acc regs -> 2 waves/SIMD) made the 268 MB gather latency-bound at 1.3 TB/s.

typedef __attribute__((ext_vector_type(8))) short short8;
typedef __attribute__((ext_vector_type(4))) float float4v;

static __device__ __forceinline__ unsigned short f2bf(float f) {
    union { float f; uint32_t i; } v; v.f = f;
    uint32_t r = v.i + 0x7FFFu + ((v.i >> 16) & 1u);
    return (unsigned short)(r >> 16);
}

// pack 8 int32 (0/1) -> 8 packed bf16 {0.0, 1.0}  (fallback path)
static __device__ __forceinline__ short8 pack01(int4 a, int4 b) {
    union { uint32_t u[4]; short8 s; } v;
    v.u[0] = (uint32_t)(a.x | (a.y << 16)) * 0x3F80u;
    v.u[1] = (uint32_t)(a.z | (a.w << 16)) * 0x3F80u;
    v.u[2] = (uint32_t)(b.x | (b.y << 16)) * 0x3F80u;
    v.u[3] = (uint32_t)(b.z | (b.w << 16)) * 0x3F80u;
    return v.s;
}

// expand 8 bits -> 8 packed bf16 {0.0, 1.0}.
// Bit-spread: S = ((B * 0x8040201008040201) >> 7) & 0x0101..01 gives byte k = bit (7-k).
static __device__ __forceinline__ short8 expand8(uint32_t B) {
    uint64_t S = ((uint64_t)B * 0x8040201008040201ull >> 7) & 0x0101010101010101ull;
    uint32_t lo = (uint32_t)S;          // bytes {b7,b6,b5,b4}
    uint32_t hi = (uint32_t)(S >> 32);  // bytes {b3,b2,b1,b0}
    union { uint32_t u[4]; short8 s; } r;
    r.u[0] = ((hi >> 24) | (((hi >> 16) & 0xFFu) << 16)) * 0x3F80u;  // e0,e1
    r.u[1] = (((hi >> 8) & 0xFFu) | ((hi & 0xFFu) << 16)) * 0x3F80u; // e2,e3
    r.u[2] = ((lo >> 24) | (((lo >> 16) & 0xFFu) << 16)) * 0x3F80u;  // e4,e5
    r.u[3] = (((lo >> 8) & 0xFFu) | ((lo & 0xFFu) << 16)) * 0x3F80u; // e6,e7
    return r.s;
}

// ---- WT[n][k] = bf16(W[k][n]) : 128x256 k-major ----
__global__ void k_transpose_w(const float* __restrict__ W, unsigned short* __restrict__ WT) {
    __shared__ unsigned short tile[32][33];
    int tx = threadIdx.x & 31, ty = threadIdx.x >> 5;
    int n0 = blockIdx.x * 32, k0 = blockIdx.y * 32;
    for (int i = 0; i < 4; i++)
        tile[ty + 8 * i][tx] = f2bf(W[(k0 + ty + 8 * i) * 128 + n0 + tx]);
    __syncthreads();
    for (int i = 0; i < 4; i++)
        WT[(size_t)(n0 + ty + 8 * i) * 256 + k0 + tx] = tile[tx][ty + 8 * i];
}

// ---- fused: h = F@W+b (MFMA) -> w = exp(h.a2w+a2b) -> whT rows 0..128 ----
__global__ __launch_bounds__(256) void k_h_fused(const float* __restrict__ F,
                                                 const unsigned short* __restrict__ WT,
                                                 const float* __restrict__ bvec,
                                                 const float* __restrict__ a2w,
                                                 const float* __restrict__ a2b,
                                                 unsigned short* __restrict__ whT) {
    __shared__ __align__(16) unsigned short As[64 * 72];
    __shared__ __align__(16) unsigned short Bs[128 * 72];
    __shared__ __align__(16) unsigned short T[129 * 72];   // [col][row_local]
    __shared__ float bs[128], aw[128], ab_s;

    int t = threadIdx.x, lane = t & 63, wave = t >> 6;
    int rb = blockIdx.x * 64;
    if (t < 128) { bs[t] = bvec[t]; aw[t] = a2w[t]; }
    if (t == 0) ab_s = a2b[0];

    float4v acc[8];
    for (int c = 0; c < 8; c++) acc[c] = (float4v)0.0f;

    for (int kt = 0; kt < 4; kt++) {
        int k0 = kt * 64;
        for (int i = 0; i < 2; i++) {                       // A: 64x64 fp32 -> bf16
            int flat = t + 256 * i, row = flat >> 3, part = flat & 7;
            const float* fp = F + (size_t)(rb + row) * 256 + k0 + part * 8;
            float4 v0 = *reinterpret_cast<const float4*>(fp);
            float4 v1 = *reinterpret_cast<const float4*>(fp + 4);
            uint4 v;
            v.x = f2bf(v0.x) | ((uint32_t)f2bf(v0.y) << 16);
            v.y = f2bf(v0.z) | ((uint32_t)f2bf(v0.w) << 16);
            v.z = f2bf(v1.x) | ((uint32_t)f2bf(v1.y) << 16);
            v.w = f2bf(v1.z) | ((uint32_t)f2bf(v1.w) << 16);
            *reinterpret_cast<uint4*>(&As[row * 72 + part * 8]) = v;
        }
        for (int i = 0; i < 4; i++) {                       // B: 128x64 bf16 k-major
            int flat = t + 256 * i, n = flat >> 3, part = flat & 7;
            *reinterpret_cast<uint4*>(&Bs[n * 72 + part * 8]) =
                *reinterpret_cast<const uint4*>(WT + (size_t)n * 256 + k0 + part * 8);
        }
        __syncthreads();
        int m = lane & 15, kq = lane >> 4;
        for (int ks = 0; ks < 2; ks++) {
            short8 af = *reinterpret_cast<const short8*>(&As[(wave * 16 + m) * 72 + ks * 32 + kq * 8]);
            for (int c = 0; c < 8; c++) {
                short8 bfr = *reinterpret_cast<const short8*>(&Bs[(c * 16 + m) * 72 + ks * 32 + kq * 8]);
                acc[c] = __builtin_amdgcn_mfma_f32_16x16x32_bf16(af, bfr, acc[c], 0, 0, 0);
            }
        }
        __syncthreads();
    }

    // epilogue: bias, per-row a2 dot (reduce over 16-lane m-group), exp, scale
    int m = lane & 15, kq = lane >> 4;
    float hv[8][4], part[4];
    for (int r = 0; r < 4; r++) part[r] = 0.0f;
    for (int c = 0; c < 8; c++) {
        float bb = bs[c * 16 + m], a = aw[c * 16 + m];
        for (int r = 0; r < 4; r++) { hv[c][r] = acc[c][r] + bb; part[r] += hv[c][r] * a; }
    }
    for (int off = 1; off < 16; off <<= 1)
        for (int r = 0; r < 4; r++) part[r] += __shfl_xor(part[r], off, 64);
    float wr[4];
    for (int r = 0; r < 4; r++) {
        float e = fminf(fmaxf(part[r] + ab_s, -60.0f), 60.0f);
        wr[r] = expf(e);
    }
    int rl = wave * 16 + kq * 4;
    for (int c = 0; c < 8; c++)
        for (int r = 0; r < 4; r++)
            T[(c * 16 + m) * 72 + rl + r] = f2bf(hv[c][r] * wr[r]);
    if (m == 0)
        for (int r = 0; r < 4; r++)
            T[128 * 72 + rl + r] = f2bf(wr[r]);
    __syncthreads();

    for (int i = 0; i < 5; i++) {                           // 129 rows x 64 shorts
        int flat = t + 256 * i;
        if (flat < 1032) {
            int row = flat >> 3, part = flat & 7;
            *reinterpret_cast<uint4*>(whT + (size_t)row * 8192 + rb + part * 8) =
                *reinterpret_cast<const uint4*>(&T[row * 72 + part * 8]);
        }
    }
}

// ---- prepass: adj int32 -> bitmask (8 MB), also zeroes C ----
// 8192 blocks x 256. Each wave: 2048 consecutive ints -> 256 bytes of mask.
// Reads are 256B/instr coalesced; __ballot packs 64 lanes -> u64.
__global__ __launch_bounds__(256) void k_adjbits(const int* __restrict__ adj,
                                                 uint32_t* __restrict__ adjb,
                                                 float* __restrict__ C) {
    int gt = blockIdx.x * 256 + threadIdx.x;
    if (gt < 8192 * 144) C[gt] = 0.0f;                      // fold C-zeroing in

    int wid = gt >> 6;                                      // 0..32767
    int lane = threadIdx.x & 63;
    const int* p = adj + (size_t)wid * 2048;
    uint64_t mymask = 0;
    #pragma unroll 8
    for (int j = 0; j < 32; j++) {
        int v = p[j * 64 + lane];
        unsigned long long msk = __ballot(v != 0);
        if (lane == j) mymask = msk;
    }
    if (lane < 32)
        *reinterpret_cast<uint64_t*>((char*)adjb + (size_t)wid * 256 + (size_t)lane * 8) = mymask;
}

// ---- KMAIN: C[8192][144] += adj @ whT^T from the bitmask ----
// 1024 blocks x 4 waves. Wave: 32 rows x K-chunk 512 (16 ksplits).
// A-side = 8 dwords of bitmask per 4 iters (L2-resident); bf16 expansion in VALU.
// Waves of a block share a rowset -> LDS reduction -> 2304 global atomics/block.
__global__ __launch_bounds__(256) void k_agg(const uint32_t* __restrict__ adjb,
                                             const unsigned short* __restrict__ whT,
                                             float* __restrict__ C) {
    __shared__ float red[32 * 145];                         // padded: kq-rows hit distinct banks
    int t = threadIdx.x;
    int wid = blockIdx.x * 4 + (t >> 6);
    int lane = t & 63;
    int m = lane & 15, kq = lane >> 4;
    int rowset = wid >> 4, ksplit = wid & 15;               // 256 rowsets x 16 ksplits
    int rb = rowset * 32;

    float4v acc[2][9];
    #pragma unroll
    for (int s = 0; s < 2; s++)
        for (int c = 0; c < 9; c++) acc[s][c] = (float4v)0.0f;

    // word index: row*256 words + ksplit*16 words + i  (i-th 32-bit chunk of K)
    const uint32_t* w0 = adjb + (size_t)(rb + m) * 256 + ksplit * 16;
    const uint32_t* w1 = w0 + (size_t)16 * 256;
    const unsigned short* bp = whT + (size_t)m * 8192 + ksplit * 512 + kq * 8;
    uint32_t sh = kq * 8;

    #pragma unroll 4
    for (int i = 0; i < 16; i++) {
        uint32_t U0 = w0[i], U1 = w1[i];
        short8 af0 = expand8((U0 >> sh) & 0xFFu);
        short8 af1 = expand8((U1 >> sh) & 0xFFu);
        #pragma unroll
        for (int c = 0; c < 9; c++) {
            short8 bf = *reinterpret_cast<const short8*>(bp + i * 32 + (size_t)c * 16 * 8192);
            acc[0][c] = __builtin_amdgcn_mfma_f32_16x16x32_bf16(af0, bf, acc[0][c], 0, 0, 0);
            acc[1][c] = __builtin_amdgcn_mfma_f32_16x16x32_bf16(af1, bf, acc[1][c], 0, 0, 0);
        }
    }

    // block-level LDS reduction (4 waves, same rowset, ksplits 4g..4g+3)
    #pragma unroll
    for (int i = 0; i < 19; i++) {
        int f = t + 256 * i;
        if (f < 32 * 145) red[f] = 0.0f;
    }
    __syncthreads();
    #pragma unroll
    for (int s = 0; s < 2; s++)
        for (int c = 0; c < 9; c++)
            for (int rr = 0; rr < 4; rr++)
                atomicAdd(&red[(s * 16 + kq * 4 + rr) * 145 + c * 16 + m], acc[s][c][rr]);
    __syncthreads();
    #pragma unroll
    for (int i = 0; i < 18; i++) {                          // 32*144 = 4608 = 256*18
        int f = t + 256 * i;
        int r = f / 144, cc = f - r * 144;
        atomicAdd(&C[(size_t)(rb + r) * 144 + cc], red[r * 145 + cc]);
    }
}

// ---- fallback KMAIN (ws too small for bitmask): v4 path ----
__global__ __launch_bounds__(256) void k_agg_fb(const int* __restrict__ adj,
                                                const unsigned short* __restrict__ whT,
                                                float* __restrict__ C) {
    int wid = blockIdx.x * 4 + (threadIdx.x >> 6);
    int lane = threadIdx.x & 63;
    int m = lane & 15, kq = lane >> 4;
    int rowset = wid >> 4, ksplit = wid & 15;
    int rb = rowset * 32;
    int kbase = ksplit * 512;

    float4v acc[2][9];
    #pragma unroll
    for (int s = 0; s < 2; s++)
        for (int c = 0; c < 9; c++) acc[s][c] = (float4v)0.0f;

    const int* a0 = adj + (size_t)(rb + m) * 8192 + kbase + kq * 8;
    const int* a1 = a0 + (size_t)16 * 8192;
    const unsigned short* bp = whT + (size_t)m * 8192 + kbase + kq * 8;

    #pragma unroll 4
    for (int kk = 0; kk < 512; kk += 32) {
        int4 x0 = *reinterpret_cast<const int4*>(a0 + kk);
        int4 x1 = *reinterpret_cast<const int4*>(a0 + kk + 4);
        int4 y0 = *reinterpret_cast<const int4*>(a1 + kk);
        int4 y1 = *reinterpret_cast<const int4*>(a1 + kk + 4);
        short8 af0 = pack01(x0, x1);
        short8 af1 = pack01(y0, y1);
        #pragma unroll
        for (int c = 0; c < 9; c++) {
            short8 bf = *reinterpret_cast<const short8*>(bp + kk + (size_t)c * 16 * 8192);
            acc[0][c] = __builtin_amdgcn_mfma_f32_16x16x32_bf16(af0, bf, acc[0][c], 0, 0, 0);
            acc[1][c] = __builtin_amdgcn_mfma_f32_16x16x32_bf16(af1, bf, acc[1][c], 0, 0, 0);
        }
    }

    #pragma unroll
    for (int s = 0; s < 2; s++)
        for (int c = 0; c < 9; c++)
            for (int rr = 0; rr < 4; rr++)
                atomicAdd(&C[(size_t)(rb + s * 16 + kq * 4 + rr) * 144 + c * 16 + m],
                          acc[s][c][rr]);
}

// ---- out[j][c] = fp32: C[j][c] / C[j][128] ----
__global__ void k_epi(const float* __restrict__ C, float* __restrict__ out) {
    int flat = blockIdx.x * 256 + threadIdx.x;   // 8192*32
    int j = flat >> 5, c4 = (flat & 31) * 4;
    float4 v = *reinterpret_cast<const float4*>(C + (size_t)j * 144 + c4);
    float rden = 1.0f / C[(size_t)j * 144 + 128];
    float4 o;
    o.x = v.x * rden; o.y = v.y * rden; o.z = v.z * rden; o.w = v.w * rden;
    *reinterpret_cast<float4*>(out + (size_t)j * 128 + c4) = o;
}

extern "C" void kernel_launch(void* const* d_in, const int* in_sizes, int n_in,
                              void* d_out, int out_size, void* d_ws, size_t ws_size,
                              hipStream_t stream) {
    const float* F   = (const float*)d_in[0];     // [8192][256]
    const int*   adj = (const int*)d_in[1];       // [8192][8192] 0/1
    const float* W   = (const float*)d_in[2];     // [256][128]
    const float* bv  = (const float*)d_in[3];     // [128]
    const float* a2w = (const float*)d_in[6];     // [128]  (a1 cancels; d_in[4],[5] unused)
    const float* a2b = (const float*)d_in[7];     // [1]
    float* out = (float*)d_out;                   // [8192][128]

    char* ws = (char*)d_ws;
    unsigned short* whT = (unsigned short*)(ws);            // 2,359,296 B (144 x 8192 bf16)
    float*          Cws = (float*)(ws + 2359296);           // 4,718,592 B (8192 x 144 fp32)
    unsigned short* WT  = (unsigned short*)(ws + 7077888);  //    65,536 B
    uint32_t*       adjb = (uint32_t*)(ws + 7143424);       // 8,388,608 B (total 15,532,032)

    k_transpose_w<<<dim3(4, 8), 256, 0, stream>>>(W, WT);
    k_h_fused<<<128, 256, 0, stream>>>(F, WT, bv, a2w, a2b, whT);
    if (ws_size >= 15532032) {
        k_adjbits<<<8192, 256, 0, stream>>>(adj, adjb, Cws);   // zeroes Cws too
        k_agg<<<1024, 256, 0, stream>>>(adjb, whT, Cws);
    } else {
        hipMemsetAsync(Cws, 0, (size_t)8192 * 144 * sizeof(float), stream);
        k_agg_fb<<<1024, 256, 0, stream>>>(adj, whT, Cws);
    }
    k_epi<<<1024, 256, 0, stream>>>(Cws, out);
}

// Round 3
// 500.072 us; speedup vs baseline: 1.0418x; 1.0418x over previous
//
#include <hip/hip_runtime.h>
#include <hip/hip_bf16.h>
#include <stdint.h>

// GAT forward, N=8192, IN=256, OUT=128. Inputs fp32 (adj int32), output fp32.
// softmax_j(a1_i + a2_j | adj) == adj_ij*exp(a2_j)/sum_j adj_ij*exp(a2_j)  (a1 cancels)
// -> out = (adj @ (w*h)) / (adj @ w). adj packs to an 8 MB bitmask (k_adjbits,
// coalesced ballot stream = the one unavoidable 268 MB read).
// v6: k_agg's B operand moves from row-major whT (16 cache lines per short8 load,
// ~288 L2 requests/iter/wave -> request-rate bound ~170us in v4 AND v5) to
// MFMA-fragment-major whB: record (i,c) = 64 lanes x 16 B, so every B load is one
// contiguous 1 KB wave transaction. L2-BW floor for B = 1.18 GB / 34.5 TB/s = 34us.

typedef __attribute__((ext_vector_type(8))) short short8;
typedef __attribute__((ext_vector_type(4))) float float4v;

static __device__ __forceinline__ unsigned short f2bf(float f) {
    union { float f; uint32_t i; } v; v.f = f;
    uint32_t r = v.i + 0x7FFFu + ((v.i >> 16) & 1u);
    return (unsigned short)(r >> 16);
}

// pack 8 int32 (0/1) -> 8 packed bf16 {0.0, 1.0}  (fallback path)
static __device__ __forceinline__ short8 pack01(int4 a, int4 b) {
    union { uint32_t u[4]; short8 s; } v;
    v.u[0] = (uint32_t)(a.x | (a.y << 16)) * 0x3F80u;
    v.u[1] = (uint32_t)(a.z | (a.w << 16)) * 0x3F80u;
    v.u[2] = (uint32_t)(b.x | (b.y << 16)) * 0x3F80u;
    v.u[3] = (uint32_t)(b.z | (b.w << 16)) * 0x3F80u;
    return v.s;
}

// expand 8 bits -> 8 packed bf16 {0.0, 1.0}.
// Bit-spread: S = ((B * 0x8040201008040201) >> 7) & 0x0101..01 gives byte k = bit (7-k).
static __device__ __forceinline__ short8 expand8(uint32_t B) {
    uint64_t S = ((uint64_t)B * 0x8040201008040201ull >> 7) & 0x0101010101010101ull;
    uint32_t lo = (uint32_t)S;          // bytes {b7,b6,b5,b4}
    uint32_t hi = (uint32_t)(S >> 32);  // bytes {b3,b2,b1,b0}
    union { uint32_t u[4]; short8 s; } r;
    r.u[0] = ((hi >> 24) | (((hi >> 16) & 0xFFu) << 16)) * 0x3F80u;  // e0,e1
    r.u[1] = (((hi >> 8) & 0xFFu) | ((hi & 0xFFu) << 16)) * 0x3F80u; // e2,e3
    r.u[2] = ((lo >> 24) | (((lo >> 16) & 0xFFu) << 16)) * 0x3F80u;  // e4,e5
    r.u[3] = (((lo >> 8) & 0xFFu) | ((lo & 0xFFu) << 16)) * 0x3F80u; // e6,e7
    return r.s;
}

// ---- WT[n][k] = bf16(W[k][n]) : 128x256 k-major ----
__global__ void k_transpose_w(const float* __restrict__ W, unsigned short* __restrict__ WT) {
    __shared__ unsigned short tile[32][33];
    int tx = threadIdx.x & 31, ty = threadIdx.x >> 5;
    int n0 = blockIdx.x * 32, k0 = blockIdx.y * 32;
    for (int i = 0; i < 4; i++)
        tile[ty + 8 * i][tx] = f2bf(W[(k0 + ty + 8 * i) * 128 + n0 + tx]);
    __syncthreads();
    for (int i = 0; i < 4; i++)
        WT[(size_t)(n0 + ty + 8 * i) * 256 + k0 + tx] = tile[tx][ty + 8 * i];
}

// ---- fused: h = F@W+b (MFMA) -> w = exp(h.a2w+a2b) -> whT rows 0..128 + whB frags ----
__global__ __launch_bounds__(256) void k_h_fused(const float* __restrict__ F,
                                                 const unsigned short* __restrict__ WT,
                                                 const float* __restrict__ bvec,
                                                 const float* __restrict__ a2w,
                                                 const float* __restrict__ a2b,
                                                 unsigned short* __restrict__ whT,
                                                 unsigned short* __restrict__ whB) {
    __shared__ __align__(16) unsigned short As[64 * 72];
    __shared__ __align__(16) unsigned short Bs[128 * 72];
    __shared__ __align__(16) unsigned short T[129 * 72];   // [col][row_local]
    __shared__ float bs[128], aw[128], ab_s;

    int t = threadIdx.x, lane = t & 63, wave = t >> 6;
    int rb = blockIdx.x * 64;
    if (t < 128) { bs[t] = bvec[t]; aw[t] = a2w[t]; }
    if (t == 0) ab_s = a2b[0];

    float4v acc[8];
    for (int c = 0; c < 8; c++) acc[c] = (float4v)0.0f;

    for (int kt = 0; kt < 4; kt++) {
        int k0 = kt * 64;
        for (int i = 0; i < 2; i++) {                       // A: 64x64 fp32 -> bf16
            int flat = t + 256 * i, row = flat >> 3, part = flat & 7;
            const float* fp = F + (size_t)(rb + row) * 256 + k0 + part * 8;
            float4 v0 = *reinterpret_cast<const float4*>(fp);
            float4 v1 = *reinterpret_cast<const float4*>(fp + 4);
            uint4 v;
            v.x = f2bf(v0.x) | ((uint32_t)f2bf(v0.y) << 16);
            v.y = f2bf(v0.z) | ((uint32_t)f2bf(v0.w) << 16);
            v.z = f2bf(v1.x) | ((uint32_t)f2bf(v1.y) << 16);
            v.w = f2bf(v1.z) | ((uint32_t)f2bf(v1.w) << 16);
            *reinterpret_cast<uint4*>(&As[row * 72 + part * 8]) = v;
        }
        for (int i = 0; i < 4; i++) {                       // B: 128x64 bf16 k-major
            int flat = t + 256 * i, n = flat >> 3, part = flat & 7;
            *reinterpret_cast<uint4*>(&Bs[n * 72 + part * 8]) =
                *reinterpret_cast<const uint4*>(WT + (size_t)n * 256 + k0 + part * 8);
        }
        __syncthreads();
        int m = lane & 15, kq = lane >> 4;
        for (int ks = 0; ks < 2; ks++) {
            short8 af = *reinterpret_cast<const short8*>(&As[(wave * 16 + m) * 72 + ks * 32 + kq * 8]);
            for (int c = 0; c < 8; c++) {
                short8 bfr = *reinterpret_cast<const short8*>(&Bs[(c * 16 + m) * 72 + ks * 32 + kq * 8]);
                acc[c] = __builtin_amdgcn_mfma_f32_16x16x32_bf16(af, bfr, acc[c], 0, 0, 0);
            }
        }
        __syncthreads();
    }

    // epilogue: bias, per-row a2 dot (reduce over 16-lane m-group), exp, scale
    int m = lane & 15, kq = lane >> 4;
    float hv[8][4], part[4];
    for (int r = 0; r < 4; r++) part[r] = 0.0f;
    for (int c = 0; c < 8; c++) {
        float bb = bs[c * 16 + m], a = aw[c * 16 + m];
        for (int r = 0; r < 4; r++) { hv[c][r] = acc[c][r] + bb; part[r] += hv[c][r] * a; }
    }
    for (int off = 1; off < 16; off <<= 1)
        for (int r = 0; r < 4; r++) part[r] += __shfl_xor(part[r], off, 64);
    float wr[4];
    for (int r = 0; r < 4; r++) {
        float e = fminf(fmaxf(part[r] + ab_s, -60.0f), 60.0f);
        wr[r] = expf(e);
    }
    int rl = wave * 16 + kq * 4;
    for (int c = 0; c < 8; c++)
        for (int r = 0; r < 4; r++)
            T[(c * 16 + m) * 72 + rl + r] = f2bf(hv[c][r] * wr[r]);
    if (m == 0)
        for (int r = 0; r < 4; r++)
            T[128 * 72 + rl + r] = f2bf(wr[r]);
    __syncthreads();

    // (a) row-major whT (fallback path consumer)
    for (int i = 0; i < 5; i++) {                           // 129 rows x 64 shorts
        int flat = t + 256 * i;
        if (flat < 1032) {
            int row = flat >> 3, part = flat & 7;
            *reinterpret_cast<uint4*>(whT + (size_t)row * 8192 + rb + part * 8) =
                *reinterpret_cast<const uint4*>(&T[row * 72 + part * 8]);
        }
    }
    // (b) fragment-major whB: record (ig, c) = 64 lanes x 8 shorts;
    //     lane l holds B[k = ig*32 + (l>>4)*8 + r][col = c*16 + (l&15)], r=0..7.
    int ig0 = rb >> 5;                                      // this block covers ig0, ig0+1
    if (t < 128) {                                          // zero pad-cols 129..143 (c=8, m>=1)
        int il = t >> 6, l = t & 63;
        if ((l & 15) != 0) {
            uint4 z = make_uint4(0u, 0u, 0u, 0u);
            *reinterpret_cast<uint4*>(whB + ((size_t)((ig0 + il) * 9 + 8) * 64 + l) * 8) = z;
        }
    }
    for (int i = 0; i < 5; i++) {
        int flat = t + 256 * i;
        if (flat < 1032) {
            int col = flat >> 3, pt = flat & 7;
            int ig = ig0 + (pt >> 2), kq2 = pt & 3;
            int c = col >> 4, mm = col & 15;
            *reinterpret_cast<uint4*>(whB + ((size_t)(ig * 9 + c) * 64 + kq2 * 16 + mm) * 8) =
                *reinterpret_cast<const uint4*>(&T[col * 72 + pt * 8]);
        }
    }
}

// ---- prepass: adj int32 -> bitmask (8 MB), also zeroes C ----
// 8192 blocks x 256. Each wave: 2048 consecutive ints -> 256 bytes of mask.
__global__ __launch_bounds__(256) void k_adjbits(const int* __restrict__ adj,
                                                 uint32_t* __restrict__ adjb,
                                                 float* __restrict__ C) {
    int gt = blockIdx.x * 256 + threadIdx.x;
    if (gt < 8192 * 144) C[gt] = 0.0f;                      // fold C-zeroing in

    int wid = gt >> 6;                                      // 0..32767
    int lane = threadIdx.x & 63;
    const int* p = adj + (size_t)wid * 2048;
    uint64_t mymask = 0;
    #pragma unroll 8
    for (int j = 0; j < 32; j++) {
        int v = p[j * 64 + lane];
        unsigned long long msk = __ballot(v != 0);
        if (lane == j) mymask = msk;
    }
    if (lane < 32)
        *reinterpret_cast<uint64_t*>((char*)adjb + (size_t)wid * 256 + (size_t)lane * 8) = mymask;
}

// ---- KMAIN: C[8192][144] += adj @ wh from bitmask A + fragment-major B ----
// 1024 blocks x 4 waves. Wave: 32 rows x K-chunk 512 (16 ksplits).
// B load = one contiguous 1 KB wave transaction per (i,c). A = 2 dwords/iter.
// Waves of a block share a rowset -> LDS reduction -> 4608 global atomics/block.
__global__ __launch_bounds__(256) void k_agg(const uint32_t* __restrict__ adjb,
                                             const unsigned short* __restrict__ whB,
                                             float* __restrict__ C) {
    __shared__ float red[32 * 145];
    int t = threadIdx.x;
    int wid = blockIdx.x * 4 + (t >> 6);
    int lane = t & 63;
    int m = lane & 15, kq = lane >> 4;
    int rowset = wid >> 4, ksplit = wid & 15;               // 256 rowsets x 16 ksplits
    int rb = rowset * 32;

    float4v acc[2][9];
    #pragma unroll
    for (int s = 0; s < 2; s++)
        for (int c = 0; c < 9; c++) acc[s][c] = (float4v)0.0f;

    const uint32_t* w0 = adjb + (size_t)(rb + m) * 256 + ksplit * 16;
    const uint32_t* w1 = w0 + (size_t)16 * 256;
    const unsigned short* bp = whB + ((size_t)(ksplit * 16) * 576 + (size_t)lane) * 8;
    uint32_t sh = kq * 8;

    #pragma unroll 4
    for (int i = 0; i < 16; i++) {
        uint32_t U0 = w0[i], U1 = w1[i];
        short8 af0 = expand8((U0 >> sh) & 0xFFu);
        short8 af1 = expand8((U1 >> sh) & 0xFFu);
        #pragma unroll
        for (int c = 0; c < 9; c++) {
            short8 bf = *reinterpret_cast<const short8*>(bp + (size_t)i * 4608 + c * 512);
            acc[0][c] = __builtin_amdgcn_mfma_f32_16x16x32_bf16(af0, bf, acc[0][c], 0, 0, 0);
            acc[1][c] = __builtin_amdgcn_mfma_f32_16x16x32_bf16(af1, bf, acc[1][c], 0, 0, 0);
        }
    }

    // block-level LDS reduction (4 waves, same rowset, ksplits 4g..4g+3)
    #pragma unroll
    for (int i = 0; i < 19; i++) {
        int f = t + 256 * i;
        if (f < 32 * 145) red[f] = 0.0f;
    }
    __syncthreads();
    #pragma unroll
    for (int s = 0; s < 2; s++)
        for (int c = 0; c < 9; c++)
            for (int rr = 0; rr < 4; rr++)
                atomicAdd(&red[(s * 16 + kq * 4 + rr) * 145 + c * 16 + m], acc[s][c][rr]);
    __syncthreads();
    #pragma unroll
    for (int i = 0; i < 18; i++) {                          // 32*144 = 4608 = 256*18
        int f = t + 256 * i;
        int r = f / 144, cc = f - r * 144;
        atomicAdd(&C[(size_t)(rb + r) * 144 + cc], red[r * 145 + cc]);
    }
}

// ---- fallback KMAIN (ws too small for bitmask): v4 path on row-major whT ----
__global__ __launch_bounds__(256) void k_agg_fb(const int* __restrict__ adj,
                                                const unsigned short* __restrict__ whT,
                                                float* __restrict__ C) {
    int wid = blockIdx.x * 4 + (threadIdx.x >> 6);
    int lane = threadIdx.x & 63;
    int m = lane & 15, kq = lane >> 4;
    int rowset = wid >> 4, ksplit = wid & 15;
    int rb = rowset * 32;
    int kbase = ksplit * 512;

    float4v acc[2][9];
    #pragma unroll
    for (int s = 0; s < 2; s++)
        for (int c = 0; c < 9; c++) acc[s][c] = (float4v)0.0f;

    const int* a0 = adj + (size_t)(rb + m) * 8192 + kbase + kq * 8;
    const int* a1 = a0 + (size_t)16 * 8192;
    const unsigned short* bp = whT + (size_t)m * 8192 + kbase + kq * 8;

    #pragma unroll 4
    for (int kk = 0; kk < 512; kk += 32) {
        int4 x0 = *reinterpret_cast<const int4*>(a0 + kk);
        int4 x1 = *reinterpret_cast<const int4*>(a0 + kk + 4);
        int4 y0 = *reinterpret_cast<const int4*>(a1 + kk);
        int4 y1 = *reinterpret_cast<const int4*>(a1 + kk + 4);
        short8 af0 = pack01(x0, x1);
        short8 af1 = pack01(y0, y1);
        #pragma unroll
        for (int c = 0; c < 9; c++) {
            short8 bf = *reinterpret_cast<const short8*>(bp + kk + (size_t)c * 16 * 8192);
            acc[0][c] = __builtin_amdgcn_mfma_f32_16x16x32_bf16(af0, bf, acc[0][c], 0, 0, 0);
            acc[1][c] = __builtin_amdgcn_mfma_f32_16x16x32_bf16(af1, bf, acc[1][c], 0, 0, 0);
        }
    }

    #pragma unroll
    for (int s = 0; s < 2; s++)
        for (int c = 0; c < 9; c++)
            for (int rr = 0; rr < 4; rr++)
                atomicAdd(&C[(size_t)(rb + s * 16 + kq * 4 + rr) * 144 + c * 16 + m],
                          acc[s][c][rr]);
}

// ---- out[j][c] = fp32: C[j][c] / C[j][128] ----
__global__ void k_epi(const float* __restrict__ C, float* __restrict__ out) {
    int flat = blockIdx.x * 256 + threadIdx.x;   // 8192*32
    int j = flat >> 5, c4 = (flat & 31) * 4;
    float4 v = *reinterpret_cast<const float4*>(C + (size_t)j * 144 + c4);
    float rden = 1.0f / C[(size_t)j * 144 + 128];
    float4 o;
    o.x = v.x * rden; o.y = v.y * rden; o.z = v.z * rden; o.w = v.w * rden;
    *reinterpret_cast<float4*>(out + (size_t)j * 128 + c4) = o;
}

extern "C" void kernel_launch(void* const* d_in, const int* in_sizes, int n_in,
                              void* d_out, int out_size, void* d_ws, size_t ws_size,
                              hipStream_t stream) {
    const float* F   = (const float*)d_in[0];     // [8192][256]
    const int*   adj = (const int*)d_in[1];       // [8192][8192] 0/1
    const float* W   = (const float*)d_in[2];     // [256][128]
    const float* bv  = (const float*)d_in[3];     // [128]
    const float* a2w = (const float*)d_in[6];     // [128]  (a1 cancels; d_in[4],[5] unused)
    const float* a2b = (const float*)d_in[7];     // [1]
    float* out = (float*)d_out;                   // [8192][128]

    char* ws = (char*)d_ws;
    unsigned short* whT  = (unsigned short*)(ws);            // 2,359,296 B (144 x 8192 bf16)
    float*          Cws  = (float*)(ws + 2359296);           // 4,718,592 B (8192 x 144 fp32)
    unsigned short* WT   = (unsigned short*)(ws + 7077888);  //    65,536 B
    uint32_t*       adjb = (uint32_t*)(ws + 7143424);        // 8,388,608 B
    unsigned short* whB  = (unsigned short*)(ws + 15532032); // 2,359,296 B (total 17,891,328)

    k_transpose_w<<<dim3(4, 8), 256, 0, stream>>>(W, WT);
    k_h_fused<<<128, 256, 0, stream>>>(F, WT, bv, a2w, a2b, whT, whB);
    if (ws_size >= 17891328) {
        k_adjbits<<<8192, 256, 0, stream>>>(adj, adjb, Cws);   // zeroes Cws too
        k_agg<<<1024, 256, 0, stream>>>(adjb, whB, Cws);
    } else {
        hipMemsetAsync(Cws, 0, (size_t)8192 * 144 * sizeof(float), stream);
        k_agg_fb<<<1024, 256, 0, stream>>>(adj, whT, Cws);
    }
    k_epi<<<1024, 256, 0, stream>>>(Cws, out);
}

// Round 4
// 455.474 us; speedup vs baseline: 1.1438x; 1.0979x over previous
//
#include <hip/hip_runtime.h>
#include <hip/hip_bf16.h>
#include <stdint.h>

// GAT forward, N=8192, IN=256, OUT=128. Inputs fp32 (adj int32), output fp32.
// softmax_j(a1_i + a2_j | adj) == adj_ij*exp(a2_j)/sum_j adj_ij*exp(a2_j)  (a1 cancels)
// -> out = (adj @ (w*h)) / (adj @ w), with w=exp(h.a2w+a2b), h=F@W+b.
// v7 pipeline (atomic-free, fallback-free; ws alloc is ~1 GiB per harness fill):
//   k_adjbits: adj int32 -> 8 MB bitmask. int4/lane loads + 3-step shuffle pack.
//   k_hW:      h/w/whB in one 256-block VALU kernel (replaces transpose+MFMA k_h,
//              which ran 128 blocks = half the CUs at 1 wave/SIMD -> ~115us for
//              536 MFLOP of work).
//   k_agg:     bitmask x fragment-major whB -> per-wave partials P[wid] (75.5 MB,
//              coalesced streams, ZERO atomics / LDS / barriers). R1-R3 showed
//              neither A-bytes (-20us) nor B-coalescing (-21us) was k_agg's cost;
//              this isolates atomics vs load-latency.
//   k_epi:     reduce 16 partials + divide.

typedef __attribute__((ext_vector_type(8))) short short8;
typedef __attribute__((ext_vector_type(4))) float float4v;

static __device__ __forceinline__ unsigned short f2bf(float f) {
    union { float f; uint32_t i; } v; v.f = f;
    uint32_t r = v.i + 0x7FFFu + ((v.i >> 16) & 1u);
    return (unsigned short)(r >> 16);
}

// round fp32 to bf16 precision, keep as fp32 (matches MFMA-bf16 numerics)
static __device__ __forceinline__ float bfr(float x) {
    union { float f; uint32_t u; } v; v.f = x;
    uint32_t r = (v.u + 0x7FFFu + ((v.u >> 16) & 1u)) & 0xFFFF0000u;
    union { uint32_t u; float f; } o; o.u = r;
    return o.f;
}

// expand 8 bits -> 8 packed bf16 {0.0, 1.0}.
static __device__ __forceinline__ short8 expand8(uint32_t B) {
    uint64_t S = ((uint64_t)B * 0x8040201008040201ull >> 7) & 0x0101010101010101ull;
    uint32_t lo = (uint32_t)S;          // bytes {b7,b6,b5,b4}
    uint32_t hi = (uint32_t)(S >> 32);  // bytes {b3,b2,b1,b0}
    union { uint32_t u[4]; short8 s; } r;
    r.u[0] = ((hi >> 24) | (((hi >> 16) & 0xFFu) << 16)) * 0x3F80u;  // e0,e1
    r.u[1] = (((hi >> 8) & 0xFFu) | ((hi & 0xFFu) << 16)) * 0x3F80u; // e2,e3
    r.u[2] = ((lo >> 24) | (((lo >> 16) & 0xFFu) << 16)) * 0x3F80u;  // e4,e5
    r.u[3] = (((lo >> 8) & 0xFFu) | ((lo & 0xFFu) << 16)) * 0x3F80u; // e6,e7
    return r.s;
}

// ---- prepass: adj int32 -> bitmask. 4096 blocks x 256 (wave = half a row). ----
// Per iter: 64 lanes x int4 = 1 KB coalesced read -> 32 B of mask via shuffle pack.
__global__ __launch_bounds__(256) void k_adjbits(const int* __restrict__ adj,
                                                 uint32_t* __restrict__ adjb) {
    int t = threadIdx.x, lane = t & 63;
    int wv = blockIdx.x * 4 + (t >> 6);           // 0..16383
    int row = wv >> 1, half = wv & 1;
    const int4* p = reinterpret_cast<const int4*>(adj + (size_t)row * 8192 + half * 4096) + lane;
    uint32_t* ob = adjb + (size_t)row * 256 + half * 128;
    #pragma unroll 4
    for (int kk = 0; kk < 16; kk++) {
        int4 v = p[kk * 64];
        uint32_t nib = (v.x != 0 ? 1u : 0u) | (v.y != 0 ? 2u : 0u) |
                       (v.z != 0 ? 4u : 0u) | (v.w != 0 ? 8u : 0u);
        uint32_t q = nib | (((uint32_t)__shfl_xor((int)nib, 1)) << 4);   // lanes %2==0: bits 0-7
        q |= ((uint32_t)__shfl_xor((int)q, 2)) << 8;                     // lanes %4==0: bits 0-15
        q |= ((uint32_t)__shfl_xor((int)q, 4)) << 16;                    // lanes %8==0: bits 0-31
        if ((lane & 7) == 0) ob[kk * 8 + (lane >> 3)] = q;
    }
}

// ---- h = F@W+b, w = exp(h.a2w+a2b), emit fragment-major whB ----
// 256 blocks x 256 threads; block = 32 rows (= one ig). thread: row=t>>3, g=t&7
// owns cols g*16..g*16+15. F and W staged in LDS as bf16-rounded fp32.
__global__ __launch_bounds__(256) void k_hW(const float* __restrict__ F,
                                            const float* __restrict__ W,
                                            const float* __restrict__ bvec,
                                            const float* __restrict__ a2w,
                                            const float* __restrict__ a2b,
                                            unsigned short* __restrict__ whB) {
    __shared__ float Fs[32 * 256];     // 32 KB
    __shared__ float Ws[64 * 128];     // 32 KB (one kt-chunk of W)
    __shared__ float bs[128], aws[128], wls[32];
    __shared__ float ab_s;

    int t = threadIdx.x;
    int row = t >> 3, g = t & 7;
    int ig = blockIdx.x, j0 = ig * 32;

    if (t < 128) { bs[t] = bvec[t]; aws[t] = a2w[t]; }
    if (t == 0) ab_s = a2b[0];

    // stage F rows (8192 floats = 2048 float4), bf16-rounded
    #pragma unroll
    for (int i = 0; i < 8; i++) {
        int flat = t + 256 * i;                   // float4 index
        int fr = flat >> 6, fp_ = (flat & 63) << 2;
        float4 v = *reinterpret_cast<const float4*>(F + (size_t)(j0 + fr) * 256 + fp_);
        float4 o; o.x = bfr(v.x); o.y = bfr(v.y); o.z = bfr(v.z); o.w = bfr(v.w);
        *reinterpret_cast<float4*>(&Fs[fr * 256 + fp_]) = o;
    }

    float h[16];
    #pragma unroll
    for (int i = 0; i < 16; i++) h[i] = 0.0f;

    for (int kt = 0; kt < 4; kt++) {
        if (kt) __syncthreads();
        // stage W rows kt*64..+63 (8192 floats)
        #pragma unroll
        for (int i = 0; i < 8; i++) {
            int flat = t + 256 * i;
            int wr = flat >> 5, wp = (flat & 31) << 2;
            float4 v = *reinterpret_cast<const float4*>(W + (size_t)(kt * 64 + wr) * 128 + wp);
            float4 o; o.x = bfr(v.x); o.y = bfr(v.y); o.z = bfr(v.z); o.w = bfr(v.w);
            *reinterpret_cast<float4*>(&Ws[wr * 128 + wp]) = o;
        }
        __syncthreads();
        for (int kk = 0; kk < 64; kk++) {
            float f = Fs[row * 256 + kt * 64 + kk];
            #pragma unroll
            for (int i = 0; i < 16; i++)
                h[i] += f * Ws[kk * 128 + g * 16 + i];
        }
    }

    // bias + a2-dot (reduce over the 8 g-lanes of this row) + exp
    float part = 0.0f;
    #pragma unroll
    for (int i = 0; i < 16; i++) {
        h[i] += bs[g * 16 + i];
        part += h[i] * aws[g * 16 + i];
    }
    part += __shfl_xor(part, 1);
    part += __shfl_xor(part, 2);
    part += __shfl_xor(part, 4);
    float wv = expf(fminf(fmaxf(part + ab_s, -60.0f), 60.0f));
    if (g == 0) wls[row] = wv;

    // whB record (ig,c): lane l=(kq,m), elem r holds B[k=ig*32+kq*8+r][c*16+m].
    // thread (row,g): c=g, m=i, kq=row>>3, r=row&7.
    int kq = row >> 3, r = row & 7;
    #pragma unroll
    for (int i = 0; i < 16; i++) {
        unsigned short u = f2bf(h[i] * wv);
        whB[((size_t)(ig * 9 + g) * 64 + kq * 16 + i) * 8 + r] = u;
    }
    __syncthreads();
    // c=8 record: col 128 = w (denominator), cols 129..143 = 0
    if (t < 64) {
        int m0 = t & 15, kq2 = t >> 4;
        uint4 val = make_uint4(0u, 0u, 0u, 0u);
        if (m0 == 0) {
            uint32_t u0 = (uint32_t)f2bf(wls[kq2 * 8 + 0]) | ((uint32_t)f2bf(wls[kq2 * 8 + 1]) << 16);
            uint32_t u1 = (uint32_t)f2bf(wls[kq2 * 8 + 2]) | ((uint32_t)f2bf(wls[kq2 * 8 + 3]) << 16);
            uint32_t u2 = (uint32_t)f2bf(wls[kq2 * 8 + 4]) | ((uint32_t)f2bf(wls[kq2 * 8 + 5]) << 16);
            uint32_t u3 = (uint32_t)f2bf(wls[kq2 * 8 + 6]) | ((uint32_t)f2bf(wls[kq2 * 8 + 7]) << 16);
            val = make_uint4(u0, u1, u2, u3);
        }
        *reinterpret_cast<uint4*>(whB + ((size_t)(ig * 9 + 8) * 64 + t) * 8) = val;
    }
}

// ---- KMAIN: per-wave partials, zero atomics/LDS/barriers ----
// 1024 blocks x 4 waves; wave = (rowset 32 rows, ksplit K-chunk 512).
// P[wid][72][64]: 72 coalesced 256 B stores per wave.
__global__ __launch_bounds__(256) void k_agg(const uint32_t* __restrict__ adjb,
                                             const unsigned short* __restrict__ whB,
                                             float* __restrict__ P) {
    int t = threadIdx.x;
    int wid = blockIdx.x * 4 + (t >> 6);
    int lane = t & 63;
    int m = lane & 15, kq = lane >> 4;
    int rowset = wid >> 4, ksplit = wid & 15;     // 256 rowsets x 16 ksplits
    int rb = rowset * 32;

    float4v acc[2][9];
    #pragma unroll
    for (int s = 0; s < 2; s++)
        for (int c = 0; c < 9; c++) acc[s][c] = (float4v)0.0f;

    const uint32_t* w0 = adjb + (size_t)(rb + m) * 256 + ksplit * 16;
    const uint32_t* w1 = w0 + (size_t)16 * 256;
    const unsigned short* bp = whB + ((size_t)(ksplit * 16) * 576 + (size_t)lane) * 8;
    uint32_t sh = kq * 8;

    #pragma unroll 4
    for (int i = 0; i < 16; i++) {
        uint32_t U0 = w0[i], U1 = w1[i];
        short8 af0 = expand8((U0 >> sh) & 0xFFu);
        short8 af1 = expand8((U1 >> sh) & 0xFFu);
        #pragma unroll
        for (int c = 0; c < 9; c++) {
            short8 bf = *reinterpret_cast<const short8*>(bp + (size_t)i * 4608 + c * 512);
            acc[0][c] = __builtin_amdgcn_mfma_f32_16x16x32_bf16(af0, bf, acc[0][c], 0, 0, 0);
            acc[1][c] = __builtin_amdgcn_mfma_f32_16x16x32_bf16(af1, bf, acc[1][c], 0, 0, 0);
        }
    }

    float* o = P + (size_t)wid * 4608 + lane;
    #pragma unroll
    for (int s = 0; s < 2; s++)
        for (int c = 0; c < 9; c++)
            for (int rr = 0; rr < 4; rr++)
                o[((s * 9 + c) * 4 + rr) * 64] = acc[s][c][rr];
}

// ---- reduce 16 ksplit-partials + divide. 256 blocks (one rowset each). ----
__global__ __launch_bounds__(256) void k_epi(const float* __restrict__ P,
                                             float* __restrict__ out) {
    __shared__ float den[32];
    int t = threadIdx.x;
    int g = blockIdx.x;
    const float* base = P + (size_t)g * 16 * 4608;

    float r[18];
    #pragma unroll
    for (int i = 0; i < 18; i++) {
        float s = 0.0f;
        #pragma unroll 4
        for (int ks = 0; ks < 16; ks++)
            s += base[(size_t)ks * 4608 + t + 256 * i];
        r[i] = s;
        int p = t + 256 * i;
        int instr = p >> 6, lane = p & 63;
        int c = (instr >> 2) % 9, m = lane & 15;
        if (c == 8 && m == 0) {
            int s16 = (instr >= 36) ? 16 : 0;
            den[s16 + (lane >> 4) * 4 + (instr & 3)] = s;
        }
    }
    __syncthreads();
    #pragma unroll
    for (int i = 0; i < 18; i++) {
        int p = t + 256 * i;
        int instr = p >> 6, lane = p & 63;
        int s16 = (instr >= 36) ? 16 : 0;
        int c = (instr >> 2) % 9, rr = instr & 3;
        int kq = lane >> 4, m = lane & 15;
        if (c < 8) {
            int jl = s16 + kq * 4 + rr;
            out[((size_t)(g * 32 + jl)) * 128 + c * 16 + m] = r[i] / den[jl];
        }
    }
}

extern "C" void kernel_launch(void* const* d_in, const int* in_sizes, int n_in,
                              void* d_out, int out_size, void* d_ws, size_t ws_size,
                              hipStream_t stream) {
    const float* F   = (const float*)d_in[0];     // [8192][256]
    const int*   adj = (const int*)d_in[1];       // [8192][8192] 0/1
    const float* W   = (const float*)d_in[2];     // [256][128]
    const float* bv  = (const float*)d_in[3];     // [128]
    const float* a2w = (const float*)d_in[6];     // [128]  (a1 cancels; d_in[4],[5] unused)
    const float* a2b = (const float*)d_in[7];     // [1]
    float* out = (float*)d_out;                   // [8192][128]

    char* ws = (char*)d_ws;
    unsigned short* whB  = (unsigned short*)(ws);            //  2,359,296 B (2304 x 8 x 64 x 2)
    uint32_t*       adjb = (uint32_t*)(ws + 2359296);        //  8,388,608 B (8192 x 256 words)
    float*          P    = (float*)(ws + 10747904);          // 75,497,472 B (4096 x 4608 fp32)
                                                             // total 86,245,376 (< ~1 GiB ws)

    k_hW<<<256, 256, 0, stream>>>(F, W, bv, a2w, a2b, whB);
    k_adjbits<<<4096, 256, 0, stream>>>(adj, adjb);
    k_agg<<<1024, 256, 0, stream>>>(adjb, whB, P);
    k_epi<<<256, 256, 0, stream>>>(P, out);
}